// Round 1
// baseline (795.713 us; speedup 1.0000x reference)
//
#include <hip/hip_runtime.h>
#include <hip/hip_bf16.h>

#define N_NODES 20000
#define E_EDGES 400000
#define LATENT 128
#define H1 256
#define HIDDEN 512
#define OUT_D 64
#define HEADS 4
#define NEG_SLOPE 0.2f

// ---------------- GEMM: C = act(A[M,K] @ B[K,N] + bias) ----------------
// 16x16 tile, one output per thread. M=20000 (divisible by 16), N,K mult of 16.
__global__ void gemm_bias_act(const float* __restrict__ A, const float* __restrict__ B,
                              const float* __restrict__ bias, float* __restrict__ C,
                              int M, int N, int K, int do_relu) {
    __shared__ float As[16][16];
    __shared__ float Bs[16][17];
    int ty = threadIdx.y, tx = threadIdx.x;
    int row = blockIdx.y * 16 + ty;
    int col = blockIdx.x * 16 + tx;
    float acc = 0.f;
    for (int k0 = 0; k0 < K; k0 += 16) {
        As[ty][tx] = A[row * K + k0 + tx];
        Bs[ty][tx] = B[(k0 + ty) * N + col];
        __syncthreads();
#pragma unroll
        for (int kk = 0; kk < 16; kk++) acc += As[ty][kk] * Bs[kk][tx];
        __syncthreads();
    }
    float v = acc + (bias ? bias[col] : 0.f);
    if (do_relu) v = fmaxf(v, 0.f);
    C[row * N + col] = v;
}

// ---------------- attention coefficients: a_src/a_dst [N, HEADS] ----------------
// one wave (64 lanes) per (node, head); lane d handles dim d.
__global__ void att_coef_kernel(const float* __restrict__ h,
                                const float* __restrict__ att_src,
                                const float* __restrict__ att_dst,
                                float* __restrict__ a_src, float* __restrict__ a_dst) {
    int wave = blockIdx.x * (blockDim.x >> 6) + (threadIdx.x >> 6);
    int lane = threadIdx.x & 63;
    if (wave >= N_NODES * HEADS) return;
    int head = wave & (HEADS - 1);
    float hv = h[wave * OUT_D + lane];
    float vs = hv * att_src[head * OUT_D + lane];
    float vd = hv * att_dst[head * OUT_D + lane];
#pragma unroll
    for (int off = 32; off > 0; off >>= 1) {
        vs += __shfl_down(vs, off, 64);
        vd += __shfl_down(vd, off, 64);
    }
    if (lane == 0) {
        a_src[wave] = vs;
        a_dst[wave] = vd;
    }
}

__device__ __forceinline__ unsigned int float_to_ordered(float f) {
    unsigned int u = __float_as_uint(f);
    return (u & 0x80000000u) ? ~u : (u | 0x80000000u);
}
__device__ __forceinline__ float ordered_to_float(unsigned int u) {
    return __uint_as_float((u & 0x80000000u) ? (u ^ 0x80000000u) : ~u);
}

// ---------------- pass A: leaky-relu logits + segment max ----------------
// thread t -> (edge, head). E' = E + N (self loops appended).
__global__ void edge_logits_kernel(const int* __restrict__ ei,
                                   const float* __restrict__ a_src,
                                   const float* __restrict__ a_dst,
                                   float* __restrict__ e_buf,
                                   unsigned int* __restrict__ m_ord) {
    int t = blockIdx.x * blockDim.x + threadIdx.x;
    const int total = (E_EDGES + N_NODES) * HEADS;
    if (t >= total) return;
    int eid = t >> 2, head = t & 3;
    int s, d;
    if (eid < E_EDGES) { s = ei[eid]; d = ei[E_EDGES + eid]; }
    else { s = d = eid - E_EDGES; }
    float v = a_src[s * HEADS + head] + a_dst[d * HEADS + head];
    v = (v > 0.f) ? v : NEG_SLOPE * v;
    e_buf[t] = v;
    atomicMax(&m_ord[d * HEADS + head], float_to_ordered(v));
}

// ---------------- pass B: exp(e - m) + segment sum ----------------
__global__ void edge_exp_kernel(const int* __restrict__ ei,
                                const unsigned int* __restrict__ m_ord,
                                float* __restrict__ e_buf,
                                float* __restrict__ denom) {
    int t = blockIdx.x * blockDim.x + threadIdx.x;
    const int total = (E_EDGES + N_NODES) * HEADS;
    if (t >= total) return;
    int eid = t >> 2, head = t & 3;
    int d;
    if (eid < E_EDGES) d = ei[E_EDGES + eid];
    else d = eid - E_EDGES;
    float m = ordered_to_float(m_ord[d * HEADS + head]);
    float ex = __expf(e_buf[t] - m);
    e_buf[t] = ex;
    atomicAdd(&denom[d * HEADS + head], ex);
}

// ---------------- init out with bias ----------------
__global__ void init_out_kernel(float* __restrict__ out, const float* __restrict__ bias) {
    int t = blockIdx.x * blockDim.x + threadIdx.x;
    if (t < N_NODES * OUT_D) out[t] = bias[t & (OUT_D - 1)];
}

// ---------------- pass C: weighted scatter-add, head-mean folded in ----------------
// thread t -> (edge, out_dim). sum over 4 heads, one atomicAdd per (edge, d).
__global__ void aggregate_kernel(const int* __restrict__ ei,
                                 const float* __restrict__ h,
                                 const float* __restrict__ e_buf,
                                 const float* __restrict__ denom,
                                 float* __restrict__ out) {
    long long t = (long long)blockIdx.x * blockDim.x + threadIdx.x;
    const long long total = (long long)(E_EDGES + N_NODES) * OUT_D;
    if (t >= total) return;
    int eid = (int)(t >> 6), dd = (int)(t & 63);
    int s, d;
    if (eid < E_EDGES) { s = ei[eid]; d = ei[E_EDGES + eid]; }
    else { s = d = eid - E_EDGES; }
    float sum = 0.f;
#pragma unroll
    for (int head = 0; head < HEADS; head++) {
        float w = e_buf[eid * HEADS + head] / (denom[d * HEADS + head] + 1e-16f);
        sum += h[(s * HEADS + head) * OUT_D + dd] * w;
    }
    atomicAdd(&out[d * OUT_D + dd], 0.25f * sum);
}

extern "C" void kernel_launch(void* const* d_in, const int* in_sizes, int n_in,
                              void* d_out, int out_size, void* d_ws, size_t ws_size,
                              hipStream_t stream) {
    const float* z       = (const float*)d_in[0];
    const float* W1      = (const float*)d_in[1];
    const float* b1      = (const float*)d_in[2];
    const float* W2      = (const float*)d_in[3];
    const float* b2      = (const float*)d_in[4];
    const float* Wg      = (const float*)d_in[5];
    const float* att_src = (const float*)d_in[6];
    const float* att_dst = (const float*)d_in[7];
    const float* bias_g  = (const float*)d_in[8];
    const int*   ei      = (const int*)d_in[9];
    float* out = (float*)d_out;

    char* ws = (char*)d_ws;
    size_t off = 0;
    float* x1 = (float*)(ws + off); off += (size_t)N_NODES * H1 * 4;       // 20.48 MB
    float* x2 = (float*)(ws + off); off += (size_t)N_NODES * HIDDEN * 4;   // 40.96 MB
    float* h  = (float*)(ws + off); off += (size_t)N_NODES * HEADS * OUT_D * 4; // 20.48 MB
    float* a_src = (float*)(ws + off); off += (size_t)N_NODES * HEADS * 4;
    float* a_dst = (float*)(ws + off); off += (size_t)N_NODES * HEADS * 4;
    unsigned int* m_ord = (unsigned int*)(ws + off); size_t m_off = off; off += (size_t)N_NODES * HEADS * 4;
    float* denom = (float*)(ws + off); off += (size_t)N_NODES * HEADS * 4;
    float* e_buf = (float*)(ws + off); off += (size_t)(E_EDGES + N_NODES) * HEADS * 4;

    // zero segment-max keys (0 == ordered(-inf)) and denominators in one memset
    hipMemsetAsync(ws + m_off, 0, (size_t)N_NODES * HEADS * 8, stream);

    dim3 blk16(16, 16);
    // x1 = relu(z @ W1 + b1)
    gemm_bias_act<<<dim3(H1 / 16, N_NODES / 16), blk16, 0, stream>>>(z, W1, b1, x1, N_NODES, H1, LATENT, 1);
    // x2 = relu(x1 @ W2 + b2)
    gemm_bias_act<<<dim3(HIDDEN / 16, N_NODES / 16), blk16, 0, stream>>>(x1, W2, b2, x2, N_NODES, HIDDEN, H1, 1);
    // h = x2 @ Wg
    gemm_bias_act<<<dim3((HEADS * OUT_D) / 16, N_NODES / 16), blk16, 0, stream>>>(x2, Wg, nullptr, h, N_NODES, HEADS * OUT_D, HIDDEN, 0);

    // a_src / a_dst
    int waves_per_block = 256 / 64;
    int n_waves = N_NODES * HEADS;
    att_coef_kernel<<<(n_waves + waves_per_block - 1) / waves_per_block, 256, 0, stream>>>(h, att_src, att_dst, a_src, a_dst);

    int totalEH = (E_EDGES + N_NODES) * HEADS;
    edge_logits_kernel<<<(totalEH + 255) / 256, 256, 0, stream>>>(ei, a_src, a_dst, e_buf, m_ord);
    edge_exp_kernel<<<(totalEH + 255) / 256, 256, 0, stream>>>(ei, m_ord, e_buf, denom);

    init_out_kernel<<<(N_NODES * OUT_D + 255) / 256, 256, 0, stream>>>(out, bias_g);

    long long totalED = (long long)(E_EDGES + N_NODES) * OUT_D;
    aggregate_kernel<<<(int)((totalED + 255) / 256), 256, 0, stream>>>(ei, h, e_buf, denom, out);
}

// Round 2
// 290.740 us; speedup vs baseline: 2.7369x; 2.7369x over previous
//
#include <hip/hip_runtime.h>
#include <hip/hip_bf16.h>

#define N_NODES 20000
#define MPAD    20096   // 157 * 128
#define E_EDGES 400000
#define LATENT 128
#define H1 256
#define HIDDEN 512
#define OUT_D 64
#define HEADS 4
#define NEG_SLOPE 0.2f

typedef __attribute__((ext_vector_type(8))) __bf16 bf16x8;
typedef __attribute__((ext_vector_type(4))) float f32x4;

__device__ __forceinline__ unsigned short f2bf(float f) {
    union { float f; unsigned int u; } v; v.f = f;
    unsigned int r = v.u + 0x7fffu + ((v.u >> 16) & 1u);  // RNE
    return (unsigned short)(r >> 16);
}

// ---------------- fp32 -> bf16 convert + pad rows (for z) ----------------
__global__ void convert_pad_z(const float* __restrict__ z, unsigned short* __restrict__ zb) {
    int t = blockIdx.x * blockDim.x + threadIdx.x;
    if (t >= MPAD * LATENT) return;
    int row = t >> 7;  // LATENT = 128
    zb[t] = f2bf(row < N_NODES ? z[t] : 0.f);
}

// ---------------- fp32 [K][N] -> bf16 [N][K] transpose-convert (weights) ----------------
__global__ void convert_transpose(const float* __restrict__ W, unsigned short* __restrict__ Wt,
                                  int K, int N) {
    int t = blockIdx.x * blockDim.x + threadIdx.x;
    if (t >= K * N) return;
    int k = t / N, n = t - k * N;
    Wt[n * K + k] = f2bf(W[t]);
}

// ---------------- bf16 MFMA GEMM: C = act(A[Mpad,K] @ Bt[N,K]^T + bias) ----------------
// 128x128 tile, BK=64, 256 threads = 4 waves in 2x2 quadrants, 4x4 16x16x32 mfma per wave.
// LDS rows padded to 72 elem (144 B): fragment-read bank alias is 2-way (free, m136).
template<int OUT_BF16>
__global__ __launch_bounds__(256)
void gemm_mfma_bt(const unsigned short* __restrict__ A,
                  const unsigned short* __restrict__ Bt,
                  const float* __restrict__ bias,
                  void* __restrict__ Cv,
                  int K, int N, int do_relu) {
    constexpr int LDP = 72;
    __shared__ unsigned short As[128 * LDP];
    __shared__ unsigned short Bs[128 * LDP];
    const int tid = threadIdx.x;
    const int wave = tid >> 6, lane = tid & 63;
    const int m0 = blockIdx.y * 128, n0 = blockIdx.x * 128;
    const int wm = (wave >> 1) * 64, wn = (wave & 1) * 64;   // wave quadrant in C-tile
    const int fr = lane & 15, q = lane >> 4;                  // fragment row / quad
    const int c = tid & 7;        // staging: 16B chunk within a 64-elem row
    const int r0 = tid >> 3;      // staging: row 0..31 (+j*32)

    f32x4 acc[4][4] = {};

    for (int k0 = 0; k0 < K; k0 += 64) {
        __syncthreads();
#pragma unroll
        for (int j = 0; j < 4; j++) {
            int r = r0 + j * 32;
            bf16x8 va = *(const bf16x8*)(A  + (size_t)(m0 + r) * K + k0 + c * 8);
            bf16x8 vb = *(const bf16x8*)(Bt + (size_t)(n0 + r) * K + k0 + c * 8);
            *(bf16x8*)(As + r * LDP + c * 8) = va;
            *(bf16x8*)(Bs + r * LDP + c * 8) = vb;
        }
        __syncthreads();
#pragma unroll
        for (int kt = 0; kt < 2; kt++) {
            bf16x8 af[4], bfr[4];
#pragma unroll
            for (int t = 0; t < 4; t++) {
                af[t]  = *(const bf16x8*)(As + (wm + t * 16 + fr) * LDP + kt * 32 + q * 8);
                bfr[t] = *(const bf16x8*)(Bs + (wn + t * 16 + fr) * LDP + kt * 32 + q * 8);
            }
#pragma unroll
            for (int mt = 0; mt < 4; mt++)
#pragma unroll
                for (int nt = 0; nt < 4; nt++)
                    acc[mt][nt] = __builtin_amdgcn_mfma_f32_16x16x32_bf16(
                        af[mt], bfr[nt], acc[mt][nt], 0, 0, 0);
        }
    }

    // epilogue: C/D layout col = lane&15, row = quad*4 + reg (m89/m91-verified)
#pragma unroll
    for (int mt = 0; mt < 4; mt++) {
#pragma unroll
        for (int nt = 0; nt < 4; nt++) {
            int col = n0 + wn + nt * 16 + fr;
            float bv = bias ? bias[col] : 0.f;
            int rowb = m0 + wm + mt * 16 + q * 4;
#pragma unroll
            for (int r = 0; r < 4; r++) {
                float v = acc[mt][nt][r] + bv;
                if (do_relu) v = fmaxf(v, 0.f);
                if (OUT_BF16)
                    ((unsigned short*)Cv)[(size_t)(rowb + r) * N + col] = f2bf(v);
                else
                    ((float*)Cv)[(size_t)(rowb + r) * N + col] = v;
            }
        }
    }
}

// ---------------- attention coefficients: a_src/a_dst [N, HEADS] ----------------
__global__ void att_coef_kernel(const float* __restrict__ h,
                                const float* __restrict__ att_src,
                                const float* __restrict__ att_dst,
                                float* __restrict__ a_src, float* __restrict__ a_dst) {
    int wave = blockIdx.x * (blockDim.x >> 6) + (threadIdx.x >> 6);
    int lane = threadIdx.x & 63;
    if (wave >= N_NODES * HEADS) return;
    int head = wave & (HEADS - 1);
    float hv = h[wave * OUT_D + lane];
    float vs = hv * att_src[head * OUT_D + lane];
    float vd = hv * att_dst[head * OUT_D + lane];
#pragma unroll
    for (int off = 32; off > 0; off >>= 1) {
        vs += __shfl_down(vs, off, 64);
        vd += __shfl_down(vd, off, 64);
    }
    if (lane == 0) {
        a_src[wave] = vs;
        a_dst[wave] = vd;
    }
}

__device__ __forceinline__ unsigned int float_to_ordered(float f) {
    unsigned int u = __float_as_uint(f);
    return (u & 0x80000000u) ? ~u : (u | 0x80000000u);
}
__device__ __forceinline__ float ordered_to_float(unsigned int u) {
    return __uint_as_float((u & 0x80000000u) ? (u ^ 0x80000000u) : ~u);
}

// ---------------- pass A: leaky-relu logits + segment max ----------------
__global__ void edge_logits_kernel(const int* __restrict__ ei,
                                   const float* __restrict__ a_src,
                                   const float* __restrict__ a_dst,
                                   float* __restrict__ e_buf,
                                   unsigned int* __restrict__ m_ord) {
    int t = blockIdx.x * blockDim.x + threadIdx.x;
    const int total = (E_EDGES + N_NODES) * HEADS;
    if (t >= total) return;
    int eid = t >> 2, head = t & 3;
    int s, d;
    if (eid < E_EDGES) { s = ei[eid]; d = ei[E_EDGES + eid]; }
    else { s = d = eid - E_EDGES; }
    float v = a_src[s * HEADS + head] + a_dst[d * HEADS + head];
    v = (v > 0.f) ? v : NEG_SLOPE * v;
    e_buf[t] = v;
    atomicMax(&m_ord[d * HEADS + head], float_to_ordered(v));
}

// ---------------- pass B: exp(e - m) + segment sum ----------------
__global__ void edge_exp_kernel(const int* __restrict__ ei,
                                const unsigned int* __restrict__ m_ord,
                                float* __restrict__ e_buf,
                                float* __restrict__ denom) {
    int t = blockIdx.x * blockDim.x + threadIdx.x;
    const int total = (E_EDGES + N_NODES) * HEADS;
    if (t >= total) return;
    int eid = t >> 2, head = t & 3;
    int d;
    if (eid < E_EDGES) d = ei[E_EDGES + eid];
    else d = eid - E_EDGES;
    float m = ordered_to_float(m_ord[d * HEADS + head]);
    float ex = __expf(e_buf[t] - m);
    e_buf[t] = ex;
    atomicAdd(&denom[d * HEADS + head], ex);
}

// ---------------- init out with bias ----------------
__global__ void init_out_kernel(float* __restrict__ out, const float* __restrict__ bias) {
    int t = blockIdx.x * blockDim.x + threadIdx.x;
    if (t < N_NODES * OUT_D) out[t] = bias[t & (OUT_D - 1)];
}

// ---------------- pass C: weighted scatter-add, head-mean folded in ----------------
__global__ void aggregate_kernel(const int* __restrict__ ei,
                                 const float* __restrict__ h,
                                 const float* __restrict__ e_buf,
                                 const float* __restrict__ denom,
                                 float* __restrict__ out) {
    long long t = (long long)blockIdx.x * blockDim.x + threadIdx.x;
    const long long total = (long long)(E_EDGES + N_NODES) * OUT_D;
    if (t >= total) return;
    int eid = (int)(t >> 6), dd = (int)(t & 63);
    int s, d;
    if (eid < E_EDGES) { s = ei[eid]; d = ei[E_EDGES + eid]; }
    else { s = d = eid - E_EDGES; }
    float sum = 0.f;
#pragma unroll
    for (int head = 0; head < HEADS; head++) {
        float w = e_buf[eid * HEADS + head] / (denom[d * HEADS + head] + 1e-16f);
        sum += h[(s * HEADS + head) * OUT_D + dd] * w;
    }
    atomicAdd(&out[d * OUT_D + dd], 0.25f * sum);
}

extern "C" void kernel_launch(void* const* d_in, const int* in_sizes, int n_in,
                              void* d_out, int out_size, void* d_ws, size_t ws_size,
                              hipStream_t stream) {
    const float* z       = (const float*)d_in[0];
    const float* W1      = (const float*)d_in[1];
    const float* b1      = (const float*)d_in[2];
    const float* W2      = (const float*)d_in[3];
    const float* b2      = (const float*)d_in[4];
    const float* Wg      = (const float*)d_in[5];
    const float* att_src = (const float*)d_in[6];
    const float* att_dst = (const float*)d_in[7];
    const float* bias_g  = (const float*)d_in[8];
    const int*   ei      = (const int*)d_in[9];
    float* out = (float*)d_out;

    char* ws = (char*)d_ws;
    size_t off = 0;
    auto carve = [&](size_t bytes) { void* p = ws + off; off += (bytes + 255) & ~(size_t)255; return p; };

    unsigned short* zb  = (unsigned short*)carve((size_t)MPAD * LATENT * 2);
    unsigned short* x1b = (unsigned short*)carve((size_t)MPAD * H1 * 2);
    unsigned short* x2b = (unsigned short*)carve((size_t)MPAD * HIDDEN * 2);
    unsigned short* W1t = (unsigned short*)carve((size_t)H1 * LATENT * 2);
    unsigned short* W2t = (unsigned short*)carve((size_t)HIDDEN * H1 * 2);
    unsigned short* Wgt = (unsigned short*)carve((size_t)(HEADS * OUT_D) * HIDDEN * 2);
    float* h     = (float*)carve((size_t)MPAD * HEADS * OUT_D * 4);
    float* a_src = (float*)carve((size_t)N_NODES * HEADS * 4);
    float* a_dst = (float*)carve((size_t)N_NODES * HEADS * 4);
    char* m_base = (char*)carve((size_t)N_NODES * HEADS * 8);  // m_ord + denom contiguous
    unsigned int* m_ord = (unsigned int*)m_base;
    float* denom = (float*)(m_base + (size_t)N_NODES * HEADS * 4);
    float* e_buf = (float*)carve((size_t)(E_EDGES + N_NODES) * HEADS * 4);

    // zero segment-max keys (0 == ordered(-inf)) and denominators
    hipMemsetAsync(m_base, 0, (size_t)N_NODES * HEADS * 8, stream);

    // bf16 conversions
    convert_pad_z<<<(MPAD * LATENT + 255) / 256, 256, 0, stream>>>(z, zb);
    convert_transpose<<<(LATENT * H1 + 255) / 256, 256, 0, stream>>>(W1, W1t, LATENT, H1);
    convert_transpose<<<(H1 * HIDDEN + 255) / 256, 256, 0, stream>>>(W2, W2t, H1, HIDDEN);
    convert_transpose<<<(HIDDEN * HEADS * OUT_D + 255) / 256, 256, 0, stream>>>(Wg, Wgt, HIDDEN, HEADS * OUT_D);

    // GEMMs (MFMA)
    gemm_mfma_bt<1><<<dim3(H1 / 128, MPAD / 128), 256, 0, stream>>>(zb,  W1t, b1, x1b, LATENT, H1, 1);
    gemm_mfma_bt<1><<<dim3(HIDDEN / 128, MPAD / 128), 256, 0, stream>>>(x1b, W2t, b2, x2b, H1, HIDDEN, 1);
    gemm_mfma_bt<0><<<dim3((HEADS * OUT_D) / 128, MPAD / 128), 256, 0, stream>>>(x2b, Wgt, nullptr, h, HIDDEN, HEADS * OUT_D, 0);

    // attention + softmax + aggregate
    int waves_per_block = 256 / 64;
    int n_waves = N_NODES * HEADS;
    att_coef_kernel<<<(n_waves + waves_per_block - 1) / waves_per_block, 256, 0, stream>>>(h, att_src, att_dst, a_src, a_dst);

    int totalEH = (E_EDGES + N_NODES) * HEADS;
    edge_logits_kernel<<<(totalEH + 255) / 256, 256, 0, stream>>>(ei, a_src, a_dst, e_buf, m_ord);
    edge_exp_kernel<<<(totalEH + 255) / 256, 256, 0, stream>>>(ei, m_ord, e_buf, denom);

    init_out_kernel<<<(N_NODES * OUT_D + 255) / 256, 256, 0, stream>>>(out, bias_g);

    long long totalED = (long long)(E_EDGES + N_NODES) * OUT_D;
    aggregate_kernel<<<(int)((totalED + 255) / 256), 256, 0, stream>>>(ei, h, e_buf, denom, out);
}

// Round 3
// 243.977 us; speedup vs baseline: 3.2614x; 1.1917x over previous
//
#include <hip/hip_runtime.h>
#include <hip/hip_bf16.h>

#define N_NODES 20000
#define MPAD    20096   // 157 * 128
#define E_EDGES 400000
#define LATENT 128
#define H1 256
#define HIDDEN 512
#define OUT_D 64
#define HEADS 4
#define NEG_SLOPE 0.2f
#define NBLK_SCAN ((N_NODES + 255) / 256)   // 79

typedef __attribute__((ext_vector_type(8))) __bf16 bf16x8;
typedef __attribute__((ext_vector_type(4))) float f32x4;

__device__ __forceinline__ unsigned short f2bf(float f) {
    union { float f; unsigned int u; } v; v.f = f;
    unsigned int r = v.u + 0x7fffu + ((v.u >> 16) & 1u);  // RNE
    return (unsigned short)(r >> 16);
}
__device__ __forceinline__ float bf2f(unsigned short u) {
    union { unsigned int u; float f; } v; v.u = ((unsigned int)u) << 16;
    return v.f;
}

// ---------------- fp32 -> bf16 convert + pad rows (for z) ----------------
__global__ void convert_pad_z(const float* __restrict__ z, unsigned short* __restrict__ zb) {
    int t = blockIdx.x * blockDim.x + threadIdx.x;
    if (t >= MPAD * LATENT) return;
    int row = t >> 7;  // LATENT = 128
    zb[t] = f2bf(row < N_NODES ? z[t] : 0.f);
}

// ---------------- fp32 [K][N] -> bf16 [N][K] transpose-convert (weights) ----------------
__global__ void convert_transpose(const float* __restrict__ W, unsigned short* __restrict__ Wt,
                                  int K, int N) {
    int t = blockIdx.x * blockDim.x + threadIdx.x;
    if (t >= K * N) return;
    int k = t / N, n = t - k * N;
    Wt[n * K + k] = f2bf(W[t]);
}

// ---------------- bf16 MFMA GEMM: C = act(A[Mpad,K] @ Bt[N,K]^T + bias) ----------------
// 128x128 tile, BK=64, 256 threads = 4 waves in 2x2 quadrants, 4x4 16x16x32 mfma per wave.
template<int OUT_BF16>
__global__ __launch_bounds__(256)
void gemm_mfma_bt(const unsigned short* __restrict__ A,
                  const unsigned short* __restrict__ Bt,
                  const float* __restrict__ bias,
                  void* __restrict__ Cv,
                  int K, int N, int do_relu) {
    constexpr int LDP = 72;
    __shared__ unsigned short As[128 * LDP];
    __shared__ unsigned short Bs[128 * LDP];
    const int tid = threadIdx.x;
    const int wave = tid >> 6, lane = tid & 63;
    const int m0 = blockIdx.y * 128, n0 = blockIdx.x * 128;
    const int wm = (wave >> 1) * 64, wn = (wave & 1) * 64;
    const int fr = lane & 15, q = lane >> 4;
    const int c = tid & 7;
    const int r0 = tid >> 3;

    f32x4 acc[4][4] = {};

    for (int k0 = 0; k0 < K; k0 += 64) {
        __syncthreads();
#pragma unroll
        for (int j = 0; j < 4; j++) {
            int r = r0 + j * 32;
            bf16x8 va = *(const bf16x8*)(A  + (size_t)(m0 + r) * K + k0 + c * 8);
            bf16x8 vb = *(const bf16x8*)(Bt + (size_t)(n0 + r) * K + k0 + c * 8);
            *(bf16x8*)(As + r * LDP + c * 8) = va;
            *(bf16x8*)(Bs + r * LDP + c * 8) = vb;
        }
        __syncthreads();
#pragma unroll
        for (int kt = 0; kt < 2; kt++) {
            bf16x8 af[4], bfr[4];
#pragma unroll
            for (int t = 0; t < 4; t++) {
                af[t]  = *(const bf16x8*)(As + (wm + t * 16 + fr) * LDP + kt * 32 + q * 8);
                bfr[t] = *(const bf16x8*)(Bs + (wn + t * 16 + fr) * LDP + kt * 32 + q * 8);
            }
#pragma unroll
            for (int mt = 0; mt < 4; mt++)
#pragma unroll
                for (int nt = 0; nt < 4; nt++)
                    acc[mt][nt] = __builtin_amdgcn_mfma_f32_16x16x32_bf16(
                        af[mt], bfr[nt], acc[mt][nt], 0, 0, 0);
        }
    }

#pragma unroll
    for (int mt = 0; mt < 4; mt++) {
#pragma unroll
        for (int nt = 0; nt < 4; nt++) {
            int col = n0 + wn + nt * 16 + fr;
            float bv = bias ? bias[col] : 0.f;
            int rowb = m0 + wm + mt * 16 + q * 4;
#pragma unroll
            for (int r = 0; r < 4; r++) {
                float v = acc[mt][nt][r] + bv;
                if (do_relu) v = fmaxf(v, 0.f);
                if (OUT_BF16)
                    ((unsigned short*)Cv)[(size_t)(rowb + r) * N + col] = f2bf(v);
                else
                    ((float*)Cv)[(size_t)(rowb + r) * N + col] = v;
            }
        }
    }
}

// ---------------- attention coefficients from bf16 h ----------------
__global__ void att_coef_kernel(const unsigned short* __restrict__ hb,
                                const float* __restrict__ att_src,
                                const float* __restrict__ att_dst,
                                float* __restrict__ a_src, float* __restrict__ a_dst) {
    int wave = blockIdx.x * (blockDim.x >> 6) + (threadIdx.x >> 6);
    int lane = threadIdx.x & 63;
    if (wave >= N_NODES * HEADS) return;
    int head = wave & (HEADS - 1);
    float hv = bf2f(hb[wave * OUT_D + lane]);
    float vs = hv * att_src[head * OUT_D + lane];
    float vd = hv * att_dst[head * OUT_D + lane];
#pragma unroll
    for (int off = 32; off > 0; off >>= 1) {
        vs += __shfl_down(vs, off, 64);
        vd += __shfl_down(vd, off, 64);
    }
    if (lane == 0) {
        a_src[wave] = vs;
        a_dst[wave] = vd;
    }
}

// ---------------- CSR build ----------------
__global__ void hist_kernel(const int* __restrict__ ei, int* __restrict__ deg) {
    int t = blockIdx.x * blockDim.x + threadIdx.x;
    if (t < E_EDGES) atomicAdd(&deg[ei[E_EDGES + t]], 1);
}

// block-local inclusive scan of (deg[i]+1); t[i] = local inclusive, bsum[b] = block total
__global__ __launch_bounds__(256) void scan_a(const int* __restrict__ deg,
                                              int* __restrict__ t, int* __restrict__ bsum) {
    int i = blockIdx.x * 256 + threadIdx.x;
    int lane = threadIdx.x & 63, wave = threadIdx.x >> 6;
    int v = (i < N_NODES) ? deg[i] + 1 : 0;
    int s = v;
#pragma unroll
    for (int off = 1; off < 64; off <<= 1) {
        int u = __shfl_up(s, off, 64);
        if (lane >= off) s += u;
    }
    __shared__ int wsum[4];
    if (lane == 63) wsum[wave] = s;
    __syncthreads();
    int woff = 0;
    for (int w = 0; w < wave; w++) woff += wsum[w];
    s += woff;
    if (i < N_NODES) t[i] = s;
    if (threadIdx.x == 255) bsum[blockIdx.x] = s;
}

// single-wave exclusive scan of block sums
__global__ void scan_b(const int* __restrict__ bsum, int* __restrict__ boff) {
    int lane = threadIdx.x;  // 64 threads
    int carry = 0;
    for (int c = 0; c < (NBLK_SCAN + 63) / 64; c++) {
        int idx = c * 64 + lane;
        int v = (idx < NBLK_SCAN) ? bsum[idx] : 0;
        int s = v;
#pragma unroll
        for (int off = 1; off < 64; off <<= 1) {
            int u = __shfl_up(s, off, 64);
            if (lane >= off) s += u;
        }
        if (idx < NBLK_SCAN) boff[idx] = carry + s - v;
        carry += __shfl(s, 63, 64);
    }
}

// finalize: row_start, cursor init, self-loop placement
__global__ __launch_bounds__(256) void scan_c(const int* __restrict__ t, const int* __restrict__ deg,
                                              const int* __restrict__ boff,
                                              int* __restrict__ row_start, int* __restrict__ cursor,
                                              int* __restrict__ adj) {
    int i = blockIdx.x * 256 + threadIdx.x;
    if (i >= N_NODES) return;
    int incl = t[i] + boff[blockIdx.x];
    int start = incl - (deg[i] + 1);
    row_start[i] = start;
    cursor[i] = start;
    adj[start + deg[i]] = i;  // self-loop in last slot
}

__global__ void scatter_kernel(const int* __restrict__ ei, int* __restrict__ cursor,
                               int* __restrict__ adj) {
    int t = blockIdx.x * blockDim.x + threadIdx.x;
    if (t >= E_EDGES) return;
    int d = ei[E_EDGES + t];
    int slot = atomicAdd(&cursor[d], 1);
    adj[slot] = ei[t];
}

// ---------------- fused segment-softmax + gather-aggregate ----------------
// block = one dst node, wave = head, lane = out dim. No atomics.
__global__ __launch_bounds__(256) void fused_gat(const int* __restrict__ adj,
                                                 const int* __restrict__ row_start,
                                                 const int* __restrict__ deg,
                                                 const float* __restrict__ a_src,
                                                 const float* __restrict__ a_dst,
                                                 const unsigned short* __restrict__ hb,
                                                 const float* __restrict__ bias_g,
                                                 float* __restrict__ out) {
    const int d = blockIdx.x;
    const int wave = threadIdx.x >> 6, lane = threadIdx.x & 63;
    const int head = wave;
    const int base = row_start[d];
    const int cnt = deg[d] + 1;
    const float ad = a_dst[d * HEADS + head];

    __shared__ int   sidx[HEADS][64];
    __shared__ float wv[HEADS][64];
    __shared__ float red[HEADS][64];

    // phase 1: logits for first chunk stashed; max reduce
    float mx = -1e30f, v0 = 0.f;
    int s0 = 0;
    const bool has = (lane < cnt);
    if (has) {
        s0 = adj[base + lane];
        float v = a_src[s0 * HEADS + head] + ad;
        v0 = (v > 0.f) ? v : NEG_SLOPE * v;
        mx = v0;
    }
    for (int e = lane + 64; e < cnt; e += 64) {   // rare (deg >= 64)
        int s = adj[base + e];
        float v = a_src[s * HEADS + head] + ad;
        v = (v > 0.f) ? v : NEG_SLOPE * v;
        mx = fmaxf(mx, v);
    }
#pragma unroll
    for (int off = 32; off > 0; off >>= 1) mx = fmaxf(mx, __shfl_xor(mx, off, 64));

    // phase 1b: sum of exp
    float sm = has ? __expf(v0 - mx) : 0.f;
    for (int e = lane + 64; e < cnt; e += 64) {
        int s = adj[base + e];
        float v = a_src[s * HEADS + head] + ad;
        v = (v > 0.f) ? v : NEG_SLOPE * v;
        sm += __expf(v - mx);
    }
#pragma unroll
    for (int off = 32; off > 0; off >>= 1) sm += __shfl_xor(sm, off, 64);
    const float inv = 1.f / (sm + 1e-16f);

    if (has) {
        sidx[wave][lane] = s0;
        wv[wave][lane] = __expf(v0 - mx) * inv;
    }
    // wave-coherent LDS: no block barrier needed before same-wave reads

    // phase 2: weighted gather of bf16 h rows
    float acc = 0.f;
    const int lim = cnt < 64 ? cnt : 64;
    for (int e = 0; e < lim; e++) {
        int s = sidx[wave][e];
        float w = wv[wave][e];
        acc += w * bf2f(hb[(s * HEADS + head) * OUT_D + lane]);
    }
    for (int e = 64; e < cnt; e++) {   // rare fallback
        int s = adj[base + e];
        float v = a_src[s * HEADS + head] + ad;
        v = (v > 0.f) ? v : NEG_SLOPE * v;
        float w = __expf(v - mx) * inv;
        acc += w * bf2f(hb[(s * HEADS + head) * OUT_D + lane]);
    }

    // combine heads (mean) + bias
    red[wave][lane] = acc;
    __syncthreads();
    if (wave == 0) {
        float r = 0.25f * (red[0][lane] + red[1][lane] + red[2][lane] + red[3][lane])
                + bias_g[lane];
        out[d * OUT_D + lane] = r;
    }
}

extern "C" void kernel_launch(void* const* d_in, const int* in_sizes, int n_in,
                              void* d_out, int out_size, void* d_ws, size_t ws_size,
                              hipStream_t stream) {
    const float* z       = (const float*)d_in[0];
    const float* W1      = (const float*)d_in[1];
    const float* b1      = (const float*)d_in[2];
    const float* W2      = (const float*)d_in[3];
    const float* b2      = (const float*)d_in[4];
    const float* Wg      = (const float*)d_in[5];
    const float* att_src = (const float*)d_in[6];
    const float* att_dst = (const float*)d_in[7];
    const float* bias_g  = (const float*)d_in[8];
    const int*   ei      = (const int*)d_in[9];
    float* out = (float*)d_out;

    char* ws = (char*)d_ws;
    size_t off = 0;
    auto carve = [&](size_t bytes) { void* p = ws + off; off += (bytes + 255) & ~(size_t)255; return p; };

    unsigned short* zb  = (unsigned short*)carve((size_t)MPAD * LATENT * 2);
    unsigned short* x1b = (unsigned short*)carve((size_t)MPAD * H1 * 2);
    unsigned short* x2b = (unsigned short*)carve((size_t)MPAD * HIDDEN * 2);
    unsigned short* W1t = (unsigned short*)carve((size_t)H1 * LATENT * 2);
    unsigned short* W2t = (unsigned short*)carve((size_t)HIDDEN * H1 * 2);
    unsigned short* Wgt = (unsigned short*)carve((size_t)(HEADS * OUT_D) * HIDDEN * 2);
    unsigned short* hb  = (unsigned short*)carve((size_t)MPAD * HEADS * OUT_D * 2);
    float* a_src = (float*)carve((size_t)N_NODES * HEADS * 4);
    float* a_dst = (float*)carve((size_t)N_NODES * HEADS * 4);
    int* deg       = (int*)carve((size_t)N_NODES * 4);
    int* tmp_scan  = (int*)carve((size_t)N_NODES * 4);
    int* bsum      = (int*)carve((size_t)NBLK_SCAN * 4);
    int* boff      = (int*)carve((size_t)NBLK_SCAN * 4);
    int* row_start = (int*)carve((size_t)N_NODES * 4);
    int* cursor    = (int*)carve((size_t)N_NODES * 4);
    int* adj       = (int*)carve((size_t)(E_EDGES + N_NODES) * 4);

    hipMemsetAsync(deg, 0, (size_t)N_NODES * 4, stream);

    // bf16 conversions
    convert_pad_z<<<(MPAD * LATENT + 255) / 256, 256, 0, stream>>>(z, zb);
    convert_transpose<<<(LATENT * H1 + 255) / 256, 256, 0, stream>>>(W1, W1t, LATENT, H1);
    convert_transpose<<<(H1 * HIDDEN + 255) / 256, 256, 0, stream>>>(W2, W2t, H1, HIDDEN);
    convert_transpose<<<(HIDDEN * HEADS * OUT_D + 255) / 256, 256, 0, stream>>>(Wg, Wgt, HIDDEN, HEADS * OUT_D);

    // CSR build (overlaps GEMM-independent stream ordering anyway)
    hist_kernel<<<(E_EDGES + 255) / 256, 256, 0, stream>>>(ei, deg);
    scan_a<<<NBLK_SCAN, 256, 0, stream>>>(deg, tmp_scan, bsum);
    scan_b<<<1, 64, 0, stream>>>(bsum, boff);
    scan_c<<<NBLK_SCAN, 256, 0, stream>>>(tmp_scan, deg, boff, row_start, cursor, adj);
    scatter_kernel<<<(E_EDGES + 255) / 256, 256, 0, stream>>>(ei, cursor, adj);

    // GEMMs (MFMA)
    gemm_mfma_bt<1><<<dim3(H1 / 128, MPAD / 128), 256, 0, stream>>>(zb,  W1t, b1, x1b, LATENT, H1, 1);
    gemm_mfma_bt<1><<<dim3(HIDDEN / 128, MPAD / 128), 256, 0, stream>>>(x1b, W2t, b2, x2b, H1, HIDDEN, 1);
    gemm_mfma_bt<1><<<dim3((HEADS * OUT_D) / 128, MPAD / 128), 256, 0, stream>>>(x2b, Wgt, nullptr, hb, HIDDEN, HEADS * OUT_D, 0);

    // attention coefficients
    int waves_per_block = 256 / 64;
    int n_waves = N_NODES * HEADS;
    att_coef_kernel<<<(n_waves + waves_per_block - 1) / waves_per_block, 256, 0, stream>>>(hb, att_src, att_dst, a_src, a_dst);

    // fused softmax + aggregate (no atomics)
    fused_gat<<<N_NODES, 256, 0, stream>>>(adj, row_start, deg, a_src, a_dst, hb, bias_g, out);
}